// Round 7
// baseline (287.702 us; speedup 1.0000x reference)
//
#include <hip/hip_runtime.h>
#include <hip/hip_bf16.h>

#define NN 50000   // nodes
#define HID 256    // hidden
#define NE 800000  // edges

typedef unsigned short u16;
typedef unsigned int u32;
typedef unsigned long long u64;
typedef __attribute__((ext_vector_type(8))) short short8v;  // 8 bf16 = 4 VGPRs
typedef __attribute__((ext_vector_type(4))) float f32x4;
typedef __attribute__((ext_vector_type(4))) u32 v4u;

#define NBIN 512   // 8 dst-tiles x 64 src-tiles

__device__ __forceinline__ u16 f2bf(float v) {
    __hip_bfloat16 h = __float2bfloat16(v);
    return *reinterpret_cast<u16*>(&h);
}

__device__ __forceinline__ u32 edge_key(int src, int dst) {
    // dst-tile (0..7) major, src-tile (0..63) minor
    const u32 dt = (u32)(dst * 8) / 50000u;
    const u32 st = (u32)(src * 64) / 50000u;
    return dt * 64u + st;
}

// ---------------------------------------------------------------------------
// Prep: W1b half-major fragment layout (identical to R6).
// ---------------------------------------------------------------------------
__global__ __launch_bounds__(256)
void prep_w1b(const float* __restrict__ W1, u16* __restrict__ W1b) {
    const int g = blockIdx.x * 256 + threadIdx.x;   // 0..16383
    if (g >= 2 * 32 * 256) return;
    const int h   = g >> 13;
    const int kbg = (g >> 8) & 31;
    const int jh  = g & 255;
    u16 o[8];
    #pragma unroll
    for (int kk = 0; kk < 8; ++kk)
        o[kk] = f2bf(W1[(size_t)(h * 256 + kbg * 8 + kk) * HID + jh]);
    *(uint4*)(W1b + (size_t)g * 8) = *(uint4*)o;
}

// ---------------------------------------------------------------------------
// Kernel 1 (MFMA, block-resident B in LDS) — identical to R6.
// ---------------------------------------------------------------------------
__global__ __launch_bounds__(512)
void node_gemm(const float* __restrict__ z, const u16* __restrict__ W1b,
               const float* __restrict__ b1, u16* __restrict__ P) {
    __shared__ __align__(16) u16 Blds[32 * 256 * 8];   // 131072 B

    const int tid  = threadIdx.x;
    const int lane = tid & 63;
    const int w    = tid >> 6;            // wave 0..7
    const int l16  = lane & 15;
    const int l4   = lane >> 4;           // k-subgroup 0..3
    const int r0   = blockIdx.x * 256 + w * 32;

    short8v af[2][8];
    #pragma unroll
    for (int mi = 0; mi < 2; ++mi) {
        const int row = r0 + mi * 16 + l16;
        const bool ok = (row < NN);
        const float* zr = z + (size_t)row * HID;
        #pragma unroll
        for (int ks = 0; ks < 8; ++ks) {
            float4 v0 = make_float4(0.f, 0.f, 0.f, 0.f), v1 = v0;
            if (ok) {
                v0 = *(const float4*)(zr + ks * 32 + l4 * 8);
                v1 = *(const float4*)(zr + ks * 32 + l4 * 8 + 4);
            }
            u16 t[8] = { f2bf(v0.x), f2bf(v0.y), f2bf(v0.z), f2bf(v0.w),
                         f2bf(v1.x), f2bf(v1.y), f2bf(v1.z), f2bf(v1.w) };
            af[mi][ks] = *(short8v*)t;
        }
    }

    const uint4* Wu4 = (const uint4*)W1b;
    uint4* Lu4 = (uint4*)Blds;

    #pragma unroll
    for (int h = 0; h < 2; ++h) {
        if (h) __syncthreads();
        #pragma unroll
        for (int c = 0; c < 16; ++c)
            Lu4[c * 512 + tid] = Wu4[(size_t)h * 8192 + c * 512 + tid];
        __syncthreads();

        #pragma unroll
        for (int ni = 0; ni < 16; ++ni) {
            f32x4 acc[2] = {};
            #pragma unroll
            for (int ks = 0; ks < 8; ++ks) {
                const short8v b = *(const short8v*)
                    &Blds[((ks * 4 + l4) * 256 + ni * 16 + l16) * 8];
                #pragma unroll
                for (int mi = 0; mi < 2; ++mi)
                    acc[mi] = __builtin_amdgcn_mfma_f32_16x16x32_bf16(
                        af[mi][ks], b, acc[mi], 0, 0, 0);
            }
            const int col  = h * 256 + ni * 16 + l16;
            const float bias = (h == 0) ? b1[ni * 16 + l16] : 0.f;
            #pragma unroll
            for (int mi = 0; mi < 2; ++mi) {
                #pragma unroll
                for (int r = 0; r < 4; ++r) {
                    const int row = r0 + mi * 16 + l4 * 4 + r;
                    if (row < NN)
                        P[(size_t)row * 512 + col] = f2bf(acc[mi][r] + bias);
                }
            }
        }
    }
}

// ---------------------------------------------------------------------------
// Sort pass 1: 512-bin histogram (LDS-aggregated).
// ---------------------------------------------------------------------------
__global__ __launch_bounds__(256)
void hist_kernel(const int* __restrict__ ei, u32* __restrict__ hist) {
    __shared__ u32 h[NBIN];
    for (int i = threadIdx.x; i < NBIN; i += 256) h[i] = 0;
    __syncthreads();
    for (int e = blockIdx.x * 256 + threadIdx.x; e < NE; e += gridDim.x * 256)
        atomicAdd(&h[edge_key(ei[e], ei[NE + e])], 1u);
    __syncthreads();
    for (int i = threadIdx.x; i < NBIN; i += 256)
        if (h[i]) atomicAdd(&hist[i], h[i]);
}

// ---------------------------------------------------------------------------
// Sort pass 2: exclusive prefix scan (1 block, Hillis-Steele).
// cursor aliases hist (safe: each thread re-reads only its own slot).
// ---------------------------------------------------------------------------
__global__ __launch_bounds__(512)
void scan_kernel(u32* __restrict__ cursor, u32* __restrict__ offsets) {
    __shared__ u32 s[NBIN];
    const int tid = threadIdx.x;
    const u32 mine = cursor[tid];
    s[tid] = mine;
    __syncthreads();
    for (int off = 1; off < NBIN; off <<= 1) {
        const u32 v = (tid >= off) ? s[tid - off] : 0u;
        __syncthreads();
        s[tid] += v;
        __syncthreads();
    }
    const u32 excl = s[tid] - mine;
    cursor[tid]  = excl;
    offsets[tid] = excl;
    if (tid == NBIN - 1) offsets[NBIN] = s[NBIN - 1];   // == NE
}

// ---------------------------------------------------------------------------
// Sort pass 3: scatter into packed (src | dst<<17 | e<<34) u64 list.
// Per-block LDS aggregation: one global atomicAdd per (block, bin).
// ---------------------------------------------------------------------------
__global__ __launch_bounds__(256)
void scatter_kernel(const int* __restrict__ ei, u32* __restrict__ cursor,
                    u64* __restrict__ packed) {
    __shared__ u32 h[NBIN];
    __shared__ u32 bb[NBIN];
    for (int i = threadIdx.x; i < NBIN; i += 256) h[i] = 0;
    __syncthreads();
    const int e0 = blockIdx.x * 2048 + threadIdx.x;
    u32 key[8], idx[8];
    #pragma unroll
    for (int i = 0; i < 8; ++i) {
        const int e = e0 + i * 256;
        key[i] = 0xFFFFFFFFu;
        if (e < NE) {
            key[i] = edge_key(ei[e], ei[NE + e]);
            idx[i] = atomicAdd(&h[key[i]], 1u);
        }
    }
    __syncthreads();
    for (int i = threadIdx.x; i < NBIN; i += 256)
        bb[i] = h[i] ? atomicAdd(&cursor[i], h[i]) : 0u;
    __syncthreads();
    #pragma unroll
    for (int i = 0; i < 8; ++i) {
        if (key[i] != 0xFFFFFFFFu) {
            const int e = e0 + i * 256;
            const u64 p = (u64)(u32)ei[e] | ((u64)(u32)ei[NE + e] << 17)
                        | ((u64)(u32)e << 34);
            packed[bb[key[i]] + idx[i]] = p;
        }
    }
}

// ---------------------------------------------------------------------------
// Kernel 2 (sorted): dst-tile k pinned to XCD k via blockIdx%8 round-robin.
// dst reads (tile, 3.2MB) stay L2-resident; src reads are monotonic,
// nontemporal (stream, don't evict the dst tile).
// ---------------------------------------------------------------------------
__device__ __forceinline__ void proc_pair(u32 ua, u32 ub,
                                          float w0, float w1, float& s) {
    const float a0 = __uint_as_float(ua << 16);
    const float a1 = __uint_as_float(ua & 0xffff0000u);
    const float b0 = __uint_as_float(ub << 16);
    const float b1 = __uint_as_float(ub & 0xffff0000u);
    const float x0 = fmaxf(a0 + b0, 0.f);
    const float x1 = fmaxf(a1 + b1, 0.f);
    s = fmaf(x0, w0, s);
    s = fmaf(x1, w1, s);
}

__global__ __launch_bounds__(256)
void edge_sorted(const u64* __restrict__ packed, const u32* __restrict__ offsets,
                 const u16* __restrict__ P, const float* __restrict__ W2,
                 const float* __restrict__ b2, float* __restrict__ out) {
    const int lane = threadIdx.x & 63;
    const int sub  = lane >> 4;
    const int l16  = lane & 15;
    const int h0   = l16 * 16;

    float w[16];
    #pragma unroll
    for (int i = 0; i < 16; i += 4) {
        const float4 v = *(const float4*)(W2 + h0 + i);
        w[i] = v.x; w[i + 1] = v.y; w[i + 2] = v.z; w[i + 3] = v.w;
    }
    const float bias2 = b2[0];

    const int xcd = blockIdx.x & 7;              // round-robin -> XCD [m09]
    const int sb  = blockIdx.x >> 3;             // block within bucket group
    const u32 lo  = offsets[xcd * 64];
    const u32 hi  = offsets[xcd * 64 + 64];
    const int nb  = gridDim.x >> 3;              // blocks per bucket
    const int wib = sb * 4 + (threadIdx.x >> 6); // wave-in-bucket
    const u32 stride = (u32)nb * 4u * 4u;        // edges per sweep

    for (u32 b4 = lo + (u32)wib * 4u; b4 < hi; b4 += stride) {
        const u32 e4  = b4 + (u32)sub;
        const bool act = (e4 < hi);
        const u64 pk = act
            ? __builtin_nontemporal_load(&packed[e4]) : 0ull;
        const int src = (int)(pk & 0x1FFFFu);
        const int dst = (int)((pk >> 17) & 0x1FFFFu);
        const int eo  = (int)(pk >> 34);

        const v4u* pa = (const v4u*)(P + (size_t)src * 512 + h0);        // top
        const u16* pb = P + (size_t)dst * 512 + 256 + h0;                // bottom
        const v4u ta0 = __builtin_nontemporal_load(pa);
        const v4u ta1 = __builtin_nontemporal_load(pa + 1);
        const uint4 tb0 = *(const uint4*)(pb);
        const uint4 tb1 = *(const uint4*)(pb + 8);

        float s = 0.f;
        proc_pair(ta0.x, tb0.x, w[0],  w[1],  s);
        proc_pair(ta0.y, tb0.y, w[2],  w[3],  s);
        proc_pair(ta0.z, tb0.z, w[4],  w[5],  s);
        proc_pair(ta0.w, tb0.w, w[6],  w[7],  s);
        proc_pair(ta1.x, tb1.x, w[8],  w[9],  s);
        proc_pair(ta1.y, tb1.y, w[10], w[11], s);
        proc_pair(ta1.z, tb1.z, w[12], w[13], s);
        proc_pair(ta1.w, tb1.w, w[14], w[15], s);

        s += __shfl_xor(s, 1);
        s += __shfl_xor(s, 2);
        s += __shfl_xor(s, 4);
        s += __shfl_xor(s, 8);
        if (l16 == 0 && act) out[eo] = s + bias2;
    }
}

// ---------------------------------------------------------------------------
// Fallback edge kernel (unsorted) if ws_size is too small for the sort.
// ---------------------------------------------------------------------------
__global__ __launch_bounds__(256)
void edge_kernel(const int* __restrict__ ei, const u16* __restrict__ P,
                 const float* __restrict__ W2, const float* __restrict__ b2,
                 float* __restrict__ out) {
    const int lane = threadIdx.x & 63;
    const int sub  = lane >> 4;
    const int l16  = lane & 15;
    const int h0   = l16 * 16;

    float w[16];
    #pragma unroll
    for (int i = 0; i < 16; i += 4) {
        const float4 v = *(const float4*)(W2 + h0 + i);
        w[i] = v.x; w[i + 1] = v.y; w[i + 2] = v.z; w[i + 3] = v.w;
    }
    const float bias2 = b2[0];

    const int gwave   = (blockIdx.x * blockDim.x + threadIdx.x) >> 6;
    const int nwaves  = (gridDim.x * blockDim.x) >> 6;
    const int ngroups = NE >> 2;

    for (int g = gwave; g < ngroups; g += nwaves) {
        const int e   = g * 4 + sub;
        const int src = ei[e];
        const int dst = ei[NE + e];

        const u16* pa = P + (size_t)src * 512 + h0;
        const u16* pb = P + (size_t)dst * 512 + 256 + h0;
        const uint4 ta0 = *(const uint4*)(pa);
        const uint4 ta1 = *(const uint4*)(pa + 8);
        const uint4 tb0 = *(const uint4*)(pb);
        const uint4 tb1 = *(const uint4*)(pb + 8);

        float s = 0.f;
        proc_pair(ta0.x, tb0.x, w[0],  w[1],  s);
        proc_pair(ta0.y, tb0.y, w[2],  w[3],  s);
        proc_pair(ta0.z, tb0.z, w[4],  w[5],  s);
        proc_pair(ta0.w, tb0.w, w[6],  w[7],  s);
        proc_pair(ta1.x, tb1.x, w[8],  w[9],  s);
        proc_pair(ta1.y, tb1.y, w[10], w[11], s);
        proc_pair(ta1.z, tb1.z, w[12], w[13], s);
        proc_pair(ta1.w, tb1.w, w[14], w[15], s);

        s += __shfl_xor(s, 1);
        s += __shfl_xor(s, 2);
        s += __shfl_xor(s, 4);
        s += __shfl_xor(s, 8);
        if (l16 == 0) out[e] = s + bias2;
    }
}

// ---------------------------------------------------------------------------
// Workspace layout (bytes):
//   [0)          W1b        262144
//   [262144)     P          51200000
//   [51462144)   packed     6400000   (u64[800000], 8-aligned)
//   [57862144)   hist/cursor 2048     (u32[512], memset 0 each launch)
//   [57864192)   offsets    2052      (u32[513])
// ---------------------------------------------------------------------------
#define WS_PACKED   51462144u
#define WS_CURSOR   57862144u
#define WS_OFFSETS  57864192u
#define WS_REQ      57866256u

extern "C" void kernel_launch(void* const* d_in, const int* in_sizes, int n_in,
                              void* d_out, int out_size, void* d_ws, size_t ws_size,
                              hipStream_t stream) {
    const float* z  = (const float*)d_in[0];
    const int*   ei = (const int*)d_in[1];
    const float* W1 = (const float*)d_in[2];
    const float* b1 = (const float*)d_in[3];
    const float* W2 = (const float*)d_in[4];
    const float* b2 = (const float*)d_in[5];
    float* out = (float*)d_out;

    char* ws = (char*)d_ws;
    u16* W1b = (u16*)ws;
    u16* P   = (u16*)(ws + 262144);

    prep_w1b<<<64, 256, 0, stream>>>(W1, W1b);
    node_gemm<<<196, 512, 0, stream>>>(z, W1b, b1, P);

    if (ws_size >= WS_REQ) {
        u64* packed  = (u64*)(ws + WS_PACKED);
        u32* cursor  = (u32*)(ws + WS_CURSOR);    // doubles as hist
        u32* offsets = (u32*)(ws + WS_OFFSETS);

        hipMemsetAsync(cursor, 0, NBIN * sizeof(u32), stream);
        hist_kernel<<<256, 256, 0, stream>>>(ei, cursor);
        scan_kernel<<<1, NBIN, 0, stream>>>(cursor, offsets);
        scatter_kernel<<<(NE + 2047) / 2048, 256, 0, stream>>>(ei, cursor, packed);
        edge_sorted<<<1024, 256, 0, stream>>>(packed, offsets, P, W2, b2, out);
    } else {
        edge_kernel<<<2048, 256, 0, stream>>>(ei, P, W2, b2, out);
    }
}

// Round 8
// 244.533 us; speedup vs baseline: 1.1765x; 1.1765x over previous
//
#include <hip/hip_runtime.h>
#include <hip/hip_bf16.h>

#define NN 50000   // nodes
#define HID 256    // hidden
#define NE 800000  // edges

typedef unsigned short u16;
typedef unsigned int u32;
typedef unsigned long long u64;
typedef __attribute__((ext_vector_type(8))) short short8v;  // 8 bf16 = 4 VGPRs
typedef __attribute__((ext_vector_type(4))) float f32x4;

#define NBIN 512   // 8 dst-tiles x 64 src-tiles

__device__ __forceinline__ u16 f2bf(float v) {
    __hip_bfloat16 h = __float2bfloat16(v);
    return *reinterpret_cast<u16*>(&h);
}

__device__ __forceinline__ u32 edge_key(int src, int dst) {
    // dst-tile (0..7) major, src-tile (0..63) minor
    const u32 dt = (u32)(dst * 8) / 50000u;
    const u32 st = (u32)(src * 64) / 50000u;
    return dt * 64u + st;
}

// ---------------------------------------------------------------------------
// Prep: W1b half-major fragment layout (identical to R6/R7).
// ---------------------------------------------------------------------------
__global__ __launch_bounds__(256)
void prep_w1b(const float* __restrict__ W1, u16* __restrict__ W1b) {
    const int g = blockIdx.x * 256 + threadIdx.x;   // 0..16383
    if (g >= 2 * 32 * 256) return;
    const int h   = g >> 13;
    const int kbg = (g >> 8) & 31;
    const int jh  = g & 255;
    u16 o[8];
    #pragma unroll
    for (int kk = 0; kk < 8; ++kk)
        o[kk] = f2bf(W1[(size_t)(h * 256 + kbg * 8 + kk) * HID + jh]);
    *(uint4*)(W1b + (size_t)g * 8) = *(uint4*)o;
}

// ---------------------------------------------------------------------------
// Kernel 1 (MFMA, block-resident B in LDS) — identical to R6/R7.
// ---------------------------------------------------------------------------
__global__ __launch_bounds__(512)
void node_gemm(const float* __restrict__ z, const u16* __restrict__ W1b,
               const float* __restrict__ b1, u16* __restrict__ P) {
    __shared__ __align__(16) u16 Blds[32 * 256 * 8];   // 131072 B

    const int tid  = threadIdx.x;
    const int lane = tid & 63;
    const int w    = tid >> 6;            // wave 0..7
    const int l16  = lane & 15;
    const int l4   = lane >> 4;           // k-subgroup 0..3
    const int r0   = blockIdx.x * 256 + w * 32;

    short8v af[2][8];
    #pragma unroll
    for (int mi = 0; mi < 2; ++mi) {
        const int row = r0 + mi * 16 + l16;
        const bool ok = (row < NN);
        const float* zr = z + (size_t)row * HID;
        #pragma unroll
        for (int ks = 0; ks < 8; ++ks) {
            float4 v0 = make_float4(0.f, 0.f, 0.f, 0.f), v1 = v0;
            if (ok) {
                v0 = *(const float4*)(zr + ks * 32 + l4 * 8);
                v1 = *(const float4*)(zr + ks * 32 + l4 * 8 + 4);
            }
            u16 t[8] = { f2bf(v0.x), f2bf(v0.y), f2bf(v0.z), f2bf(v0.w),
                         f2bf(v1.x), f2bf(v1.y), f2bf(v1.z), f2bf(v1.w) };
            af[mi][ks] = *(short8v*)t;
        }
    }

    const uint4* Wu4 = (const uint4*)W1b;
    uint4* Lu4 = (uint4*)Blds;

    #pragma unroll
    for (int h = 0; h < 2; ++h) {
        if (h) __syncthreads();
        #pragma unroll
        for (int c = 0; c < 16; ++c)
            Lu4[c * 512 + tid] = Wu4[(size_t)h * 8192 + c * 512 + tid];
        __syncthreads();

        #pragma unroll
        for (int ni = 0; ni < 16; ++ni) {
            f32x4 acc[2] = {};
            #pragma unroll
            for (int ks = 0; ks < 8; ++ks) {
                const short8v b = *(const short8v*)
                    &Blds[((ks * 4 + l4) * 256 + ni * 16 + l16) * 8];
                #pragma unroll
                for (int mi = 0; mi < 2; ++mi)
                    acc[mi] = __builtin_amdgcn_mfma_f32_16x16x32_bf16(
                        af[mi][ks], b, acc[mi], 0, 0, 0);
            }
            const int col  = h * 256 + ni * 16 + l16;
            const float bias = (h == 0) ? b1[ni * 16 + l16] : 0.f;
            #pragma unroll
            for (int mi = 0; mi < 2; ++mi) {
                #pragma unroll
                for (int r = 0; r < 4; ++r) {
                    const int row = r0 + mi * 16 + l4 * 4 + r;
                    if (row < NN)
                        P[(size_t)row * 512 + col] = f2bf(acc[mi][r] + bias);
                }
            }
        }
    }
}

// ---------------------------------------------------------------------------
// Sort pass 1: 512-bin histogram (LDS-aggregated).
// ---------------------------------------------------------------------------
__global__ __launch_bounds__(256)
void hist_kernel(const int* __restrict__ ei, u32* __restrict__ hist) {
    __shared__ u32 h[NBIN];
    for (int i = threadIdx.x; i < NBIN; i += 256) h[i] = 0;
    __syncthreads();
    for (int e = blockIdx.x * 256 + threadIdx.x; e < NE; e += gridDim.x * 256)
        atomicAdd(&h[edge_key(ei[e], ei[NE + e])], 1u);
    __syncthreads();
    for (int i = threadIdx.x; i < NBIN; i += 256)
        if (h[i]) atomicAdd(&hist[i], h[i]);
}

// ---------------------------------------------------------------------------
// Sort pass 2: exclusive prefix scan (1 block, Hillis-Steele).
// ---------------------------------------------------------------------------
__global__ __launch_bounds__(512)
void scan_kernel(u32* __restrict__ cursor, u32* __restrict__ offsets) {
    __shared__ u32 s[NBIN];
    const int tid = threadIdx.x;
    const u32 mine = cursor[tid];
    s[tid] = mine;
    __syncthreads();
    for (int off = 1; off < NBIN; off <<= 1) {
        const u32 v = (tid >= off) ? s[tid - off] : 0u;
        __syncthreads();
        s[tid] += v;
        __syncthreads();
    }
    const u32 excl = s[tid] - mine;
    cursor[tid]  = excl;
    offsets[tid] = excl;
    if (tid == NBIN - 1) offsets[NBIN] = s[NBIN - 1];   // == NE
}

// ---------------------------------------------------------------------------
// Sort pass 3: scatter into packed (src | dst<<17 | e<<34) u64 list.
// ---------------------------------------------------------------------------
__global__ __launch_bounds__(256)
void scatter_kernel(const int* __restrict__ ei, u32* __restrict__ cursor,
                    u64* __restrict__ packed) {
    __shared__ u32 h[NBIN];
    __shared__ u32 bb[NBIN];
    for (int i = threadIdx.x; i < NBIN; i += 256) h[i] = 0;
    __syncthreads();
    const int e0 = blockIdx.x * 2048 + threadIdx.x;
    u32 key[8], idx[8];
    #pragma unroll
    for (int i = 0; i < 8; ++i) {
        const int e = e0 + i * 256;
        key[i] = 0xFFFFFFFFu;
        if (e < NE) {
            key[i] = edge_key(ei[e], ei[NE + e]);
            idx[i] = atomicAdd(&h[key[i]], 1u);
        }
    }
    __syncthreads();
    for (int i = threadIdx.x; i < NBIN; i += 256)
        bb[i] = h[i] ? atomicAdd(&cursor[i], h[i]) : 0u;
    __syncthreads();
    #pragma unroll
    for (int i = 0; i < 8; ++i) {
        if (key[i] != 0xFFFFFFFFu) {
            const int e = e0 + i * 256;
            const u64 p = (u64)(u32)ei[e] | ((u64)(u32)ei[NE + e] << 17)
                        | ((u64)(u32)e << 34);
            packed[bb[key[i]] + idx[i]] = p;
        }
    }
}

// ---------------------------------------------------------------------------
// Kernel 2 (sorted): dst-tile k pinned to XCD k via blockIdx%8 round-robin.
// R8 deltas vs R7: grid 2048 (full occupancy), src loads cached (no NT —
// src rows have ~2x L2 reuse within a bin); NT only on the streamed packed.
// ---------------------------------------------------------------------------
__device__ __forceinline__ void proc_pair(u32 ua, u32 ub,
                                          float w0, float w1, float& s) {
    const float a0 = __uint_as_float(ua << 16);
    const float a1 = __uint_as_float(ua & 0xffff0000u);
    const float b0 = __uint_as_float(ub << 16);
    const float b1 = __uint_as_float(ub & 0xffff0000u);
    const float x0 = fmaxf(a0 + b0, 0.f);
    const float x1 = fmaxf(a1 + b1, 0.f);
    s = fmaf(x0, w0, s);
    s = fmaf(x1, w1, s);
}

__global__ __launch_bounds__(256)
void edge_sorted(const u64* __restrict__ packed, const u32* __restrict__ offsets,
                 const u16* __restrict__ P, const float* __restrict__ W2,
                 const float* __restrict__ b2, float* __restrict__ out) {
    const int lane = threadIdx.x & 63;
    const int sub  = lane >> 4;
    const int l16  = lane & 15;
    const int h0   = l16 * 16;

    float w[16];
    #pragma unroll
    for (int i = 0; i < 16; i += 4) {
        const float4 v = *(const float4*)(W2 + h0 + i);
        w[i] = v.x; w[i + 1] = v.y; w[i + 2] = v.z; w[i + 3] = v.w;
    }
    const float bias2 = b2[0];

    const int xcd = blockIdx.x & 7;              // round-robin -> XCD [m09]
    const int sb  = blockIdx.x >> 3;             // block within bucket group
    const u32 lo  = offsets[xcd * 64];
    const u32 hi  = offsets[xcd * 64 + 64];
    const int nb  = gridDim.x >> 3;              // blocks per bucket
    const int wib = sb * 4 + (threadIdx.x >> 6); // wave-in-bucket
    const u32 stride = (u32)nb * 4u * 4u;        // edges per sweep

    for (u32 b4 = lo + (u32)wib * 4u; b4 < hi; b4 += stride) {
        const u32 e4  = b4 + (u32)sub;
        const bool act = (e4 < hi);
        const u64 pk = act
            ? __builtin_nontemporal_load(&packed[e4]) : 0ull;
        const int src = (int)(pk & 0x1FFFFu);
        const int dst = (int)((pk >> 17) & 0x1FFFFu);
        const int eo  = (int)(pk >> 34);

        const u16* pa = P + (size_t)src * 512 + h0;        // top half
        const u16* pb = P + (size_t)dst * 512 + 256 + h0;  // bottom half
        const uint4 ta0 = *(const uint4*)(pa);
        const uint4 ta1 = *(const uint4*)(pa + 8);
        const uint4 tb0 = *(const uint4*)(pb);
        const uint4 tb1 = *(const uint4*)(pb + 8);

        float s = 0.f;
        proc_pair(ta0.x, tb0.x, w[0],  w[1],  s);
        proc_pair(ta0.y, tb0.y, w[2],  w[3],  s);
        proc_pair(ta0.z, tb0.z, w[4],  w[5],  s);
        proc_pair(ta0.w, tb0.w, w[6],  w[7],  s);
        proc_pair(ta1.x, tb1.x, w[8],  w[9],  s);
        proc_pair(ta1.y, tb1.y, w[10], w[11], s);
        proc_pair(ta1.z, tb1.z, w[12], w[13], s);
        proc_pair(ta1.w, tb1.w, w[14], w[15], s);

        s += __shfl_xor(s, 1);
        s += __shfl_xor(s, 2);
        s += __shfl_xor(s, 4);
        s += __shfl_xor(s, 8);
        if (l16 == 0 && act) out[eo] = s + bias2;
    }
}

// ---------------------------------------------------------------------------
// Fallback edge kernel (unsorted) if ws_size is too small for the sort.
// ---------------------------------------------------------------------------
__global__ __launch_bounds__(256)
void edge_kernel(const int* __restrict__ ei, const u16* __restrict__ P,
                 const float* __restrict__ W2, const float* __restrict__ b2,
                 float* __restrict__ out) {
    const int lane = threadIdx.x & 63;
    const int sub  = lane >> 4;
    const int l16  = lane & 15;
    const int h0   = l16 * 16;

    float w[16];
    #pragma unroll
    for (int i = 0; i < 16; i += 4) {
        const float4 v = *(const float4*)(W2 + h0 + i);
        w[i] = v.x; w[i + 1] = v.y; w[i + 2] = v.z; w[i + 3] = v.w;
    }
    const float bias2 = b2[0];

    const int gwave   = (blockIdx.x * blockDim.x + threadIdx.x) >> 6;
    const int nwaves  = (gridDim.x * blockDim.x) >> 6;
    const int ngroups = NE >> 2;

    for (int g = gwave; g < ngroups; g += nwaves) {
        const int e   = g * 4 + sub;
        const int src = ei[e];
        const int dst = ei[NE + e];

        const u16* pa = P + (size_t)src * 512 + h0;
        const u16* pb = P + (size_t)dst * 512 + 256 + h0;
        const uint4 ta0 = *(const uint4*)(pa);
        const uint4 ta1 = *(const uint4*)(pa + 8);
        const uint4 tb0 = *(const uint4*)(pb);
        const uint4 tb1 = *(const uint4*)(pb + 8);

        float s = 0.f;
        proc_pair(ta0.x, tb0.x, w[0],  w[1],  s);
        proc_pair(ta0.y, tb0.y, w[2],  w[3],  s);
        proc_pair(ta0.z, tb0.z, w[4],  w[5],  s);
        proc_pair(ta0.w, tb0.w, w[6],  w[7],  s);
        proc_pair(ta1.x, tb1.x, w[8],  w[9],  s);
        proc_pair(ta1.y, tb1.y, w[10], w[11], s);
        proc_pair(ta1.z, tb1.z, w[12], w[13], s);
        proc_pair(ta1.w, tb1.w, w[14], w[15], s);

        s += __shfl_xor(s, 1);
        s += __shfl_xor(s, 2);
        s += __shfl_xor(s, 4);
        s += __shfl_xor(s, 8);
        if (l16 == 0) out[e] = s + bias2;
    }
}

// ---------------------------------------------------------------------------
// Workspace layout (bytes):
//   [0)          W1b        262144
//   [262144)     P          51200000
//   [51462144)   packed     6400000   (u64[800000], 8-aligned)
//   [57862144)   hist/cursor 2048
//   [57864192)   offsets    2052
// ---------------------------------------------------------------------------
#define WS_PACKED   51462144u
#define WS_CURSOR   57862144u
#define WS_OFFSETS  57864192u
#define WS_REQ      57866256u

extern "C" void kernel_launch(void* const* d_in, const int* in_sizes, int n_in,
                              void* d_out, int out_size, void* d_ws, size_t ws_size,
                              hipStream_t stream) {
    const float* z  = (const float*)d_in[0];
    const int*   ei = (const int*)d_in[1];
    const float* W1 = (const float*)d_in[2];
    const float* b1 = (const float*)d_in[3];
    const float* W2 = (const float*)d_in[4];
    const float* b2 = (const float*)d_in[5];
    float* out = (float*)d_out;

    char* ws = (char*)d_ws;
    u16* W1b = (u16*)ws;
    u16* P   = (u16*)(ws + 262144);

    prep_w1b<<<64, 256, 0, stream>>>(W1, W1b);
    node_gemm<<<196, 512, 0, stream>>>(z, W1b, b1, P);

    if (ws_size >= WS_REQ) {
        u64* packed  = (u64*)(ws + WS_PACKED);
        u32* cursor  = (u32*)(ws + WS_CURSOR);    // doubles as hist
        u32* offsets = (u32*)(ws + WS_OFFSETS);

        hipMemsetAsync(cursor, 0, NBIN * sizeof(u32), stream);
        hist_kernel<<<256, 256, 0, stream>>>(ei, cursor);
        scan_kernel<<<1, NBIN, 0, stream>>>(cursor, offsets);
        scatter_kernel<<<(NE + 2047) / 2048, 256, 0, stream>>>(ei, cursor, packed);
        edge_sorted<<<2048, 256, 0, stream>>>(packed, offsets, P, W2, b2, out);
    } else {
        edge_kernel<<<2048, 256, 0, stream>>>(ei, P, W2, b2, out);
    }
}